// Round 1
// baseline (492.536 us; speedup 1.0000x reference)
//
#include <hip/hip_runtime.h>

#define IN_DIM   128
#define OUT_DIM  64

// ---------------------------------------------------------------------------
// Zero-fill (float4 where possible)
// ---------------------------------------------------------------------------
__global__ void zero_f4_kernel(float4* __restrict__ p, int n4) {
    int i = blockIdx.x * blockDim.x + threadIdx.x;
    int s = gridDim.x * blockDim.x;
    for (; i < n4; i += s) p[i] = make_float4(0.f, 0.f, 0.f, 0.f);
}

// ---------------------------------------------------------------------------
// h = x @ W   (x: [N,128] f32, W: [128,64] f32, h: [N,64] f32)
// Block = 256 threads = 4 waves. W staged in LDS (32 KB). One wave per row,
// lane = output column. x row staged in LDS (broadcast reads are free).
// ---------------------------------------------------------------------------
__global__ __launch_bounds__(256) void linear_kernel(
        const float* __restrict__ x, const float* __restrict__ W,
        float* __restrict__ h, int nrows) {
    __shared__ float sW[IN_DIM * OUT_DIM];   // 32 KB
    __shared__ float sx[4][IN_DIM];

    const int tid = threadIdx.x;
    for (int i = tid; i < IN_DIM * OUT_DIM; i += 256) sW[i] = W[i];
    __syncthreads();

    const int wave = tid >> 6;
    const int lane = tid & 63;

    for (int r = blockIdx.x * 4 + wave; r < nrows; r += gridDim.x * 4) {
        // stage this row of x (128 floats) — within-wave LDS RAW is safe
        sx[wave][lane]      = x[(size_t)r * IN_DIM + lane];
        sx[wave][lane + 64] = x[(size_t)r * IN_DIM + 64 + lane];

        float acc = 0.f;
#pragma unroll
        for (int k = 0; k < IN_DIM; k += 4) {
            float4 xv = *reinterpret_cast<const float4*>(&sx[wave][k]);
            acc = fmaf(xv.x, sW[(k + 0) * OUT_DIM + lane], acc);
            acc = fmaf(xv.y, sW[(k + 1) * OUT_DIM + lane], acc);
            acc = fmaf(xv.z, sW[(k + 2) * OUT_DIM + lane], acc);
            acc = fmaf(xv.w, sW[(k + 3) * OUT_DIM + lane], acc);
        }
        h[(size_t)r * OUT_DIM + lane] = acc;
    }
}

// ---------------------------------------------------------------------------
// deg[col[e]] += 1  (float accumulation; exact for counts < 2^24)
// ---------------------------------------------------------------------------
__global__ void deg_kernel(const int* __restrict__ col, float* __restrict__ deg, int E) {
    int i = blockIdx.x * blockDim.x + threadIdx.x;
    int s = gridDim.x * blockDim.x;
    for (; i < E; i += s) atomicAdd(&deg[col[i]], 1.0f);
}

// ---------------------------------------------------------------------------
// deg -> deg^(-1/2) in place (0 where deg == 0)
// ---------------------------------------------------------------------------
__global__ void dis_kernel(float* __restrict__ deg, int n) {
    int i = blockIdx.x * blockDim.x + threadIdx.x;
    int s = gridDim.x * blockDim.x;
    for (; i < n; i += s) {
        float d = deg[i];
        deg[i] = (d > 0.f) ? rsqrtf(d) : 0.f;
    }
}

// ---------------------------------------------------------------------------
// Scatter: one wave per edge, lane = output column.
//   out[col*64 + lane] += h[row*64 + lane] * dis[row] * dis[col]
// ---------------------------------------------------------------------------
__global__ __launch_bounds__(256) void scatter_kernel(
        const int* __restrict__ eidx, const float* __restrict__ h,
        const float* __restrict__ dis, float* __restrict__ out, int E) {
    const int lane = threadIdx.x & 63;
    int w        = (blockIdx.x * blockDim.x + threadIdx.x) >> 6;
    const int nw = (gridDim.x * blockDim.x) >> 6;

    for (int e = w; e < E; e += nw) {
        int r = eidx[e];
        int c = eidx[E + e];
        float norm = dis[r] * dis[c];
        float v = h[(size_t)r * OUT_DIM + lane] * norm;
        atomicAdd(&out[(size_t)c * OUT_DIM + lane], v);
    }
}

// ---------------------------------------------------------------------------
// out = PReLU(out + b)   (float4; OUT_DIM=64 so a float4 never wraps columns)
// ---------------------------------------------------------------------------
__global__ void finish_kernel(float4* __restrict__ out, const float* __restrict__ b,
                              const float* __restrict__ prelu_a, int n4) {
    const float a = prelu_a[0];
    int i = blockIdx.x * blockDim.x + threadIdx.x;
    int s = gridDim.x * blockDim.x;
    for (; i < n4; i += s) {
        int colbase = (i * 4) & (OUT_DIM - 1);
        float4 v = out[i];
        v.x += b[colbase + 0];
        v.y += b[colbase + 1];
        v.z += b[colbase + 2];
        v.w += b[colbase + 3];
        v.x = (v.x >= 0.f) ? v.x : a * v.x;
        v.y = (v.y >= 0.f) ? v.y : a * v.y;
        v.z = (v.z >= 0.f) ? v.z : a * v.z;
        v.w = (v.w >= 0.f) ? v.w : a * v.w;
        out[i] = v;
    }
}

extern "C" void kernel_launch(void* const* d_in, const int* in_sizes, int n_in,
                              void* d_out, int out_size, void* d_ws, size_t ws_size,
                              hipStream_t stream) {
    const float* x    = (const float*)d_in[0];
    const int*   eidx = (const int*)d_in[1];   // [2, E] int32 per harness convention
    const float* W    = (const float*)d_in[2];
    const float* b    = (const float*)d_in[3];
    const float* pa   = (const float*)d_in[4];
    float* out = (float*)d_out;

    const int N = in_sizes[0] / IN_DIM;        // 100000
    const int E = in_sizes[1] / 2;             // 1600000

    // workspace layout: h [N*64] floats, then deg/dis [N] floats
    float* h   = (float*)d_ws;
    float* deg = h + (size_t)N * OUT_DIM;

    // 1) zero accumulators (out and deg) — must happen every call (graph replay)
    {
        int n4 = (N * OUT_DIM) / 4;            // 6.4M / 4, exact
        zero_f4_kernel<<<2048, 256, 0, stream>>>((float4*)out, n4);
        int nd4 = (N + 3) / 4;                 // N=100000 divisible by 4
        zero_f4_kernel<<<128, 256, 0, stream>>>((float4*)deg, nd4);
    }

    // 2) h = x @ W
    linear_kernel<<<2048, 256, 0, stream>>>(x, W, h, N);

    // 3) degree over targets
    deg_kernel<<<2048, 256, 0, stream>>>(eidx + E, deg, E);

    // 4) deg -> deg^{-1/2}
    dis_kernel<<<(N + 255) / 256, 256, 0, stream>>>(deg, N);

    // 5) gather-scale-scatter
    scatter_kernel<<<2048, 256, 0, stream>>>(eidx, h, deg, out, E);

    // 6) bias + PReLU
    finish_kernel<<<2048, 256, 0, stream>>>((float4*)out, b, pa, (N * OUT_DIM) / 4);
}

// Round 2
// 327.573 us; speedup vs baseline: 1.5036x; 1.5036x over previous
//
#include <hip/hip_runtime.h>

#define IN_DIM   128
#define OUT_DIM  64

// ---------------------------------------------------------------------------
// Zero ints (grid-stride)
// ---------------------------------------------------------------------------
__global__ void zero_i_kernel(int* __restrict__ p, int n) {
    int i = blockIdx.x * blockDim.x + threadIdx.x;
    int s = gridDim.x * blockDim.x;
    for (; i < n; i += s) p[i] = 0;
}

// ---------------------------------------------------------------------------
// deg[col[e]] += 1  (int)
// ---------------------------------------------------------------------------
__global__ void degi_kernel(const int* __restrict__ col, int* __restrict__ deg, int E) {
    int i = blockIdx.x * blockDim.x + threadIdx.x;
    int s = gridDim.x * blockDim.x;
    for (; i < E; i += s) atomicAdd(&deg[col[i]], 1);
}

// ---------------------------------------------------------------------------
// dis[i] = deg>0 ? rsqrt(deg) : 0   (separate output; deg stays intact)
// ---------------------------------------------------------------------------
__global__ void dis_kernel(const int* __restrict__ deg, float* __restrict__ dis, int n) {
    int i = blockIdx.x * blockDim.x + threadIdx.x;
    int s = gridDim.x * blockDim.x;
    for (; i < n; i += s) {
        float d = (float)deg[i];
        dis[i] = (d > 0.f) ? rsqrtf(d) : 0.f;
    }
}

// ---------------------------------------------------------------------------
// hs = (x @ W) * dis[row]
// ---------------------------------------------------------------------------
__global__ __launch_bounds__(256) void linear_kernel(
        const float* __restrict__ x, const float* __restrict__ W,
        const float* __restrict__ dis, float* __restrict__ hs, int nrows) {
    __shared__ float sW[IN_DIM * OUT_DIM];   // 32 KB
    __shared__ float sx[4][IN_DIM];

    const int tid = threadIdx.x;
    for (int i = tid; i < IN_DIM * OUT_DIM; i += 256) sW[i] = W[i];
    __syncthreads();

    const int wave = tid >> 6;
    const int lane = tid & 63;

    for (int r = blockIdx.x * 4 + wave; r < nrows; r += gridDim.x * 4) {
        sx[wave][lane]      = x[(size_t)r * IN_DIM + lane];
        sx[wave][lane + 64] = x[(size_t)r * IN_DIM + 64 + lane];

        float acc = 0.f;
#pragma unroll
        for (int k = 0; k < IN_DIM; k += 4) {
            float4 xv = *reinterpret_cast<const float4*>(&sx[wave][k]);
            acc = fmaf(xv.x, sW[(k + 0) * OUT_DIM + lane], acc);
            acc = fmaf(xv.y, sW[(k + 1) * OUT_DIM + lane], acc);
            acc = fmaf(xv.z, sW[(k + 2) * OUT_DIM + lane], acc);
            acc = fmaf(xv.w, sW[(k + 3) * OUT_DIM + lane], acc);
        }
        hs[(size_t)r * OUT_DIM + lane] = acc * dis[r];
    }
}

// ---------------------------------------------------------------------------
// Prefix scan of deg -> rowptr (exclusive), 3-kernel hierarchical
// ---------------------------------------------------------------------------
__global__ void scan1_kernel(const int* __restrict__ deg, int* __restrict__ rowptr,
                             int* __restrict__ bsums, int n) {
    __shared__ int s[256];
    const int t = threadIdx.x;
    const int i = blockIdx.x * 256 + t;
    int v = (i < n) ? deg[i] : 0;
    s[t] = v;
    __syncthreads();
    for (int off = 1; off < 256; off <<= 1) {
        int tmp = (t >= off) ? s[t - off] : 0;
        __syncthreads();
        s[t] += tmp;
        __syncthreads();
    }
    if (i < n) rowptr[i] = s[t] - v;
    if (t == 255) bsums[blockIdx.x] = s[255];
}

__global__ void scan2_kernel(const int* __restrict__ bsums, int* __restrict__ boffs, int nb) {
    if (threadIdx.x == 0 && blockIdx.x == 0) {
        int run = 0;
        for (int i = 0; i < nb; ++i) { int v = bsums[i]; boffs[i] = run; run += v; }
    }
}

__global__ void scan3_kernel(int* __restrict__ rowptr, const int* __restrict__ boffs, int n) {
    int i = blockIdx.x * blockDim.x + threadIdx.x;
    int s = gridDim.x * blockDim.x;
    for (; i < n; i += s) rowptr[i] += boffs[i >> 8];
}

// ---------------------------------------------------------------------------
// Bucket fill: src[rowptr[c] + cursor[c]++] = r
// ---------------------------------------------------------------------------
__global__ void fill_kernel(const int* __restrict__ eidx, const int* __restrict__ rowptr,
                            int* __restrict__ cursor, int* __restrict__ src, int E) {
    int i = blockIdx.x * blockDim.x + threadIdx.x;
    int s = gridDim.x * blockDim.x;
    for (; i < E; i += s) {
        int r = eidx[i];
        int c = eidx[E + i];
        int pos = rowptr[c] + atomicAdd(&cursor[c], 1);
        src[pos] = r;
    }
}

// ---------------------------------------------------------------------------
// Aggregate + bias + PReLU: one wave per target node, lane = column
// ---------------------------------------------------------------------------
__global__ __launch_bounds__(256) void agg_kernel(
        const int* __restrict__ rowptr, const int* __restrict__ src,
        const float* __restrict__ hs, const float* __restrict__ dis,
        const float* __restrict__ b, const float* __restrict__ prelu_a,
        float* __restrict__ out, int N, int E) {
    const int lane = threadIdx.x & 63;
    const int node = (blockIdx.x * blockDim.x + threadIdx.x) >> 6;
    if (node >= N) return;

    const int beg = rowptr[node];
    const int end = (node + 1 < N) ? rowptr[node + 1] : E;

    float acc = 0.f;
    int p = beg;
    for (; p + 4 <= end; p += 4) {
        int r0 = src[p], r1 = src[p + 1], r2 = src[p + 2], r3 = src[p + 3];
        float v0 = hs[(size_t)r0 * OUT_DIM + lane];
        float v1 = hs[(size_t)r1 * OUT_DIM + lane];
        float v2 = hs[(size_t)r2 * OUT_DIM + lane];
        float v3 = hs[(size_t)r3 * OUT_DIM + lane];
        acc += v0 + v1 + v2 + v3;
    }
    for (; p < end; ++p) acc += hs[(size_t)src[p] * OUT_DIM + lane];

    float o = acc * dis[node] + b[lane];
    out[(size_t)node * OUT_DIM + lane] = (o >= 0.f) ? o : prelu_a[0] * o;
}

extern "C" void kernel_launch(void* const* d_in, const int* in_sizes, int n_in,
                              void* d_out, int out_size, void* d_ws, size_t ws_size,
                              hipStream_t stream) {
    const float* x    = (const float*)d_in[0];
    const int*   eidx = (const int*)d_in[1];
    const float* W    = (const float*)d_in[2];
    const float* b    = (const float*)d_in[3];
    const float* pa   = (const float*)d_in[4];
    float* out = (float*)d_out;

    const int N = in_sizes[0] / IN_DIM;        // 100000
    const int E = in_sizes[1] / 2;             // 1600000
    const int NB = (N + 255) / 256;

    // workspace layout (4-byte elements):
    float* hs     = (float*)d_ws;                        // N*64
    int*   deg    = (int*)(hs + (size_t)N * OUT_DIM);    // N
    int*   cursor = deg + N;                             // N
    int*   rowptr = cursor + N;                          // N
    float* dis    = (float*)(rowptr + N);                // N
    int*   bsums  = (int*)(dis + N);                     // NB
    int*   boffs  = bsums + NB;                          // NB
    int*   src    = boffs + NB;                          // E

    // 1) zero deg + cursor (contiguous 2N ints)
    zero_i_kernel<<<512, 256, 0, stream>>>(deg, 2 * N);

    // 2) degree over targets (int atomics)
    degi_kernel<<<2048, 256, 0, stream>>>(eidx + E, deg, E);

    // 3) dis = deg^{-1/2}
    dis_kernel<<<(N + 255) / 256, 256, 0, stream>>>(deg, dis, N);

    // 4) hs = (x @ W) * dis[row]
    linear_kernel<<<2048, 256, 0, stream>>>(x, W, dis, hs, N);

    // 5) scan deg -> rowptr (exclusive)
    scan1_kernel<<<NB, 256, 0, stream>>>(deg, rowptr, bsums, N);
    scan2_kernel<<<1, 64, 0, stream>>>(bsums, boffs, NB);
    scan3_kernel<<<512, 256, 0, stream>>>(rowptr, boffs, N);

    // 6) bucket fill
    fill_kernel<<<2048, 256, 0, stream>>>(eidx, rowptr, cursor, src, E);

    // 7) aggregate + bias + PReLU
    agg_kernel<<<(N * 64 + 255) / 256, 256, 0, stream>>>(
        rowptr, src, hs, dis, b, pa, out, N, E);
}